// Round 13
// baseline (16.938 us; speedup 1.0000x reference)
//
#include <hip/hip_runtime.h>
#include <math.h>

#define H    1024
#define NH   16
#define HD   128
#define ID   2048                 // NH*HD
#define K1_BLOCKS 2048            // exactly 8 blocks/CU, no tail round
#define EPS 1e-6f

typedef float v4f __attribute__((ext_vector_type(4)));

__device__ __forceinline__ float waveReduceSum(float v) {
#pragma unroll
    for (int off = 32; off > 0; off >>= 1) v += __shfl_down(v, off, 64);
    return v;
}
__device__ __forceinline__ float waveReduceSumAll(float v) {
#pragma unroll
    for (int off = 1; off < 64; off <<= 1) v += __shfl_xor(v, off, 64);
    return v;
}

// Kernel 1: fused matvec of x against W_qkv (rows 0..6143) / W_z (6144..8191),
// one row per wave, exactly 2048 blocks (8/CU). Extra work rides along:
//  - W_a rows: wave 0 of blocks 0..15 does row Wa[b] after its main row.
//  - conv passthrough: 2 float4/block on threads 0..1 (+1 on thread 2 for
//    b<512) -> 4608 float4 total, fully parallel.
//  - out[] zero: block 16 (K2 atomicAdds into out).
// All single-use streams (weights, conv) use nontemporal load/store.
__global__ __launch_bounds__(256) void matvec_qkvza(
    const float* __restrict__ x,
    const float* __restrict__ Wqkv,
    const float* __restrict__ Wz,
    const float* __restrict__ Wa,
    const float* __restrict__ conv,
    float* __restrict__ conv_out,
    float* __restrict__ out,
    float* __restrict__ ws_qkv,    // [6144] q|k|v
    float* __restrict__ ws_zsig,   // [2048] z*sigmoid(z)
    float* __restrict__ ws_decay)  // [16] sigmoid(a)
{
    const int b    = blockIdx.x;
    const int t    = threadIdx.x;
    const int wave = t >> 6;
    const int lane = t & 63;

    // conv passthrough (single-use stream, nt both ways)
    if (t < 2) {
        const v4f c = __builtin_nontemporal_load(&((const v4f*)conv)[b * 2 + t]);
        __builtin_nontemporal_store(c, &((v4f*)conv_out)[b * 2 + t]);
    } else if (t == 2 && b < 512) {
        const v4f c = __builtin_nontemporal_load(&((const v4f*)conv)[4096 + b]);
        __builtin_nontemporal_store(c, &((v4f*)conv_out)[4096 + b]);
    }
    // zero out[1024] = 256 float4 (block 16, one per thread)
    if (b == 16) {
        float4 z4 = {0.f, 0.f, 0.f, 0.f};
        ((float4*)out)[t] = z4;
    }

    const v4f* x4 = (const v4f*)x;
    v4f xv[4];
#pragma unroll
    for (int i = 0; i < 4; ++i) xv[i] = x4[lane + 64 * i];

    // main row r = 4b + wave (0..8191); kind is block-uniform
    {
        const int r = b * 4 + wave;
        const float* row = (r < 3 * ID) ? (Wqkv + (size_t)r * H)
                                        : (Wz + (size_t)(r - 3 * ID) * H);
        const v4f* row4 = (const v4f*)row;
        float acc = 0.f;
#pragma unroll
        for (int i = 0; i < 4; ++i) {
            const v4f w = __builtin_nontemporal_load(&row4[lane + 64 * i]);
            acc += w.x * xv[i].x + w.y * xv[i].y + w.z * xv[i].z + w.w * xv[i].w;
        }
        acc = waveReduceSum(acc);
        if (lane == 0) {
            if (r < 3 * ID) {
                ws_qkv[r] = acc;
            } else {
                const float sig = 1.f / (1.f + expf(-acc));
                ws_zsig[r - 3 * ID] = acc * sig;
            }
        }
    }

    // W_a rows: blocks 0..15, wave 0 (one extra row each)
    if (b < NH && wave == 0) {
        const v4f* row4 = (const v4f*)(Wa + (size_t)b * H);
        float acc = 0.f;
#pragma unroll
        for (int i = 0; i < 4; ++i) {
            const v4f w = __builtin_nontemporal_load(&row4[lane + 64 * i]);
            acc += w.x * xv[i].x + w.y * xv[i].y + w.z * xv[i].z + w.w * xv[i].w;
        }
        acc = waveReduceSum(acc);
        if (lane == 0) ws_decay[b] = 1.f / (1.f + expf(-acc));
    }
}

// Kernel 2 (R7/R12 champion structure): 256 blocks = (slice s = b>>4, head
// h = b&15) x 1024 threads; same-h blocks share XCD h%8 L2 so the full-head
// state read is fetched from HBM ~once per head. Wout rows (single-use)
// nontemporal-loaded into registers up front; new_state written with
// nontemporal stores (never re-read in-kernel).
__global__ __launch_bounds__(1024) void state_gate_out(
    const float* __restrict__ state_in,
    const float* __restrict__ ws_qkv,
    const float* __restrict__ ws_decay,
    const float* __restrict__ ws_zsig,
    const float* __restrict__ normw,
    const float* __restrict__ Wout,
    float* __restrict__ state_out,
    float* __restrict__ out)
{
    const int s  = blockIdx.x >> 4;
    const int h  = blockIdx.x & 15;
    const int t  = threadIdx.x;
    const int c  = t & 31;     // float4 column (e = 4c..4c+3)
    const int dg = t >> 5;     // 0..31, covers d = 4dg..4dg+3
    const int wv = t >> 6;     // wave, covers d in [8wv, 8wv+8)
    const int lane = t & 63;

    __shared__ float4 part4[16][32];   // 8 KB per-wave y partials
    __shared__ float gated[HD];
    __shared__ float red2[2];

    // ---- Wout register preload, nontemporal (single-use stream) ----
    const int rl = t >> 4;            // 0..63
    const int j  = t & 15;
    const int r  = s * 64 + rl;
    const v4f* wrow = (const v4f*)(Wout + (size_t)r * ID + h * HD);
    const v4f w0 = __builtin_nontemporal_load(&wrow[j * 2]);
    const v4f w1 = __builtin_nontemporal_load(&wrow[j * 2 + 1]);

    const float decay = ws_decay[h];
    const float4 vv = ((const float4*)(ws_qkv + 2 * ID + h * HD))[c];
    const float4 q4 = ((const float4*)(ws_qkv + h * HD))[dg];
    const float4 k4 = ((const float4*)(ws_qkv + ID + h * HD))[dg];

    const float4* sin4 = (const float4*)(state_in  + (size_t)h * HD * HD);
    v4f*          sout = (v4f*)(state_out + (size_t)h * HD * HD);

    const bool do_write = (wv == s);   // wave-uniform

    float4 acc = {0.f, 0.f, 0.f, 0.f};
    const float qs[4] = {q4.x, q4.y, q4.z, q4.w};
    const float ks[4] = {k4.x, k4.y, k4.z, k4.w};
#pragma unroll
    for (int i = 0; i < 4; ++i) {
        const int d = dg * 4 + i;
        const float4 sv = sin4[d * 32 + c];
        v4f sn;
        sn.x = sv.x * decay + ks[i] * vv.x;
        sn.y = sv.y * decay + ks[i] * vv.y;
        sn.z = sv.z * decay + ks[i] * vv.z;
        sn.w = sv.w * decay + ks[i] * vv.w;
        if (do_write) __builtin_nontemporal_store(sn, &sout[d * 32 + c]);
        acc.x += qs[i] * sn.x;
        acc.y += qs[i] * sn.y;
        acc.z += qs[i] * sn.z;
        acc.w += qs[i] * sn.w;
    }
    acc.x += __shfl_xor(acc.x, 32, 64);
    acc.y += __shfl_xor(acc.y, 32, 64);
    acc.z += __shfl_xor(acc.z, 32, 64);
    acc.w += __shfl_xor(acc.w, 32, 64);
    if (lane < 32) part4[wv][c] = acc;
    __syncthreads();

    const float* partF = (const float*)part4;
    float y = 0.f;
    if (t < HD) {
#pragma unroll
        for (int w2 = 0; w2 < 16; ++w2) y += partF[w2 * HD + t];
        const float s2 = waveReduceSumAll(y * y);
        if (lane == 0) red2[t >> 6] = s2;
    }
    __syncthreads();
    if (t < HD) {
        const float scale = rsqrtf((red2[0] + red2[1]) * (1.f / HD) + EPS);
        gated[t] = y * scale * normw[t] * ws_zsig[h * HD + t];
    }
    __syncthreads();

    {
        const v4f* g4 = (const v4f*)gated;
        const v4f g0 = g4[j * 2], g1 = g4[j * 2 + 1];
        float a = w0.x * g0.x + w0.y * g0.y + w0.z * g0.z + w0.w * g0.w
                + w1.x * g1.x + w1.y * g1.y + w1.z * g1.z + w1.w * g1.w;
        a += __shfl_xor(a, 1, 64);
        a += __shfl_xor(a, 2, 64);
        a += __shfl_xor(a, 4, 64);
        a += __shfl_xor(a, 8, 64);
        if (j == 0) atomicAdd(&out[r], a);
    }
}

extern "C" void kernel_launch(void* const* d_in, const int* in_sizes, int n_in,
                              void* d_out, int out_size, void* d_ws, size_t ws_size,
                              hipStream_t stream) {
    const float* x     = (const float*)d_in[0];
    const float* state = (const float*)d_in[1];
    const float* conv  = (const float*)d_in[2];
    const float* Wqkv  = (const float*)d_in[3];
    const float* Wz    = (const float*)d_in[4];
    const float* Wa    = (const float*)d_in[5];
    const float* normw = (const float*)d_in[6];
    const float* Wout  = (const float*)d_in[7];

    float* out       = (float*)d_out;                    // [1024]
    float* new_state = out + H;                          // [16*128*128]
    float* conv_out  = new_state + (size_t)NH * HD * HD; // [18432]

    float* ws       = (float*)d_ws;
    float* ws_qkv   = ws;               // 6144
    float* ws_zsig  = ws + 6144;        // 2048
    float* ws_decay = ws + 8192;        // 16

    matvec_qkvza<<<K1_BLOCKS, 256, 0, stream>>>(
        x, Wqkv, Wz, Wa, conv, conv_out, out, ws_qkv, ws_zsig, ws_decay);
    state_gate_out<<<NH * 16, 1024, 0, stream>>>(
        state, ws_qkv, ws_decay, ws_zsig, normw, Wout, new_state, out);
}

// Round 14
// 16.199 us; speedup vs baseline: 1.0456x; 1.0456x over previous
//
#include <hip/hip_runtime.h>
#include <math.h>

#define H    1024
#define NH   16
#define HD   128
#define ID   2048                 // NH*HD
#define NROWS_A (3*ID + ID + NH)  // 6144 qkv + 2048 z + 16 a = 8208
#define MATVEC_BLOCKS (NROWS_A / 4)   // 2052, one row per wave
#define CONV_FLOATS (3 * ID * 3)      // 18432 floats = 4608 float4
#define CONV_BLOCKS (CONV_FLOATS / 4 / 256)  // 18
#define EPS 1e-6f

typedef float v4f __attribute__((ext_vector_type(4)));

__device__ __forceinline__ float waveReduceSum(float v) {
#pragma unroll
    for (int off = 32; off > 0; off >>= 1) v += __shfl_down(v, off, 64);
    return v;
}
__device__ __forceinline__ float waveReduceSumAll(float v) {
#pragma unroll
    for (int off = 1; off < 64; off <<= 1) v += __shfl_xor(v, off, 64);
    return v;
}

// Kernel 1 (R12 champion): fused matvec of x against W_qkv/W_z/W_a, one row
// per wave. Single-use weight rows use NONTEMPORAL loads (skip cache
// allocation); x stays cached (reused by every wave).
__global__ __launch_bounds__(256) void matvec_qkvza(
    const float* __restrict__ x,
    const float* __restrict__ Wqkv,
    const float* __restrict__ Wz,
    const float* __restrict__ Wa,
    const float* __restrict__ conv,
    float* __restrict__ conv_out,
    float* __restrict__ out,       // zeroed here (K2 atomicAdds into it)
    float* __restrict__ ws_qkv,    // [6144] q|k|v
    float* __restrict__ ws_zsig,   // [2048] z*sigmoid(z)
    float* __restrict__ ws_decay)  // [16] sigmoid(a)
{
    if (blockIdx.x >= MATVEC_BLOCKS) {
        const int cb = blockIdx.x - MATVEC_BLOCKS;
        const int i = cb * 256 + threadIdx.x;
        ((float4*)conv_out)[i] = ((const float4*)conv)[i];
        if (cb == 0) {   // zero out[1024] = 256 float4
            float4 z4 = {0.f, 0.f, 0.f, 0.f};
            ((float4*)out)[threadIdx.x] = z4;
        }
        return;
    }

    const int wave = threadIdx.x >> 6;
    const int lane = threadIdx.x & 63;
    const int r = blockIdx.x * 4 + wave;

    const float* row;
    if (r < 3 * ID)           row = Wqkv + (size_t)r * H;
    else if (r < 3 * ID + ID) row = Wz   + (size_t)(r - 3 * ID) * H;
    else                      row = Wa   + (size_t)(r - 3 * ID - ID) * H;

    const v4f* row4 = (const v4f*)row;
    const v4f* x4   = (const v4f*)x;

    float acc = 0.f;
#pragma unroll
    for (int t = 0; t < 4; ++t) {
        const v4f w  = __builtin_nontemporal_load(&row4[lane + 64 * t]);
        const v4f xv = x4[lane + 64 * t];
        acc += w.x * xv.x + w.y * xv.y + w.z * xv.z + w.w * xv.w;
    }
    acc = waveReduceSum(acc);
    if (lane == 0) {
        if (r < 3 * ID) {
            ws_qkv[r] = acc;
        } else if (r < 3 * ID + ID) {
            const float sig = 1.f / (1.f + expf(-acc));
            ws_zsig[r - 3 * ID] = acc * sig;
        } else {
            ws_decay[r - 3 * ID - ID] = 1.f / (1.f + expf(-acc));
        }
    }
}

// Kernel 2 (R12 champion): 256 blocks = (slice s = b>>4, head h = b&15) x
// 1024 threads; same-h blocks share XCD h%8 L2 so the full-head state read
// is fetched from HBM ~once per head. Wout rows (single-use) loaded
// nontemporally into registers up front; state stays cached (16x reuse).
__global__ __launch_bounds__(1024) void state_gate_out(
    const float* __restrict__ state_in,
    const float* __restrict__ ws_qkv,
    const float* __restrict__ ws_decay,
    const float* __restrict__ ws_zsig,
    const float* __restrict__ normw,
    const float* __restrict__ Wout,
    float* __restrict__ state_out,
    float* __restrict__ out)
{
    const int s  = blockIdx.x >> 4;
    const int h  = blockIdx.x & 15;
    const int t  = threadIdx.x;
    const int c  = t & 31;     // float4 column (e = 4c..4c+3)
    const int dg = t >> 5;     // 0..31, covers d = 4dg..4dg+3
    const int wv = t >> 6;     // wave, covers d in [8wv, 8wv+8)
    const int lane = t & 63;

    __shared__ float4 part4[16][32];   // 8 KB per-wave y partials
    __shared__ float gated[HD];
    __shared__ float red2[2];

    // ---- Wout register preload, nontemporal (single-use stream) ----
    const int rl = t >> 4;            // 0..63
    const int j  = t & 15;
    const int r  = s * 64 + rl;
    const v4f* wrow = (const v4f*)(Wout + (size_t)r * ID + h * HD);
    const v4f w0 = __builtin_nontemporal_load(&wrow[j * 2]);
    const v4f w1 = __builtin_nontemporal_load(&wrow[j * 2 + 1]);

    const float decay = ws_decay[h];
    const float4 vv = ((const float4*)(ws_qkv + 2 * ID + h * HD))[c];
    const float4 q4 = ((const float4*)(ws_qkv + h * HD))[dg];
    const float4 k4 = ((const float4*)(ws_qkv + ID + h * HD))[dg];

    const float4* sin4 = (const float4*)(state_in  + (size_t)h * HD * HD);
    float4*       sout = (float4*)(state_out + (size_t)h * HD * HD);

    const bool do_write = (wv == s);   // wave-uniform

    float4 acc = {0.f, 0.f, 0.f, 0.f};
    const float qs[4] = {q4.x, q4.y, q4.z, q4.w};
    const float ks[4] = {k4.x, k4.y, k4.z, k4.w};
#pragma unroll
    for (int i = 0; i < 4; ++i) {
        const int d = dg * 4 + i;
        const float4 sv = sin4[d * 32 + c];
        float4 sn;
        sn.x = sv.x * decay + ks[i] * vv.x;
        sn.y = sv.y * decay + ks[i] * vv.y;
        sn.z = sv.z * decay + ks[i] * vv.z;
        sn.w = sv.w * decay + ks[i] * vv.w;
        if (do_write) sout[d * 32 + c] = sn;
        acc.x += qs[i] * sn.x;
        acc.y += qs[i] * sn.y;
        acc.z += qs[i] * sn.z;
        acc.w += qs[i] * sn.w;
    }
    acc.x += __shfl_xor(acc.x, 32, 64);
    acc.y += __shfl_xor(acc.y, 32, 64);
    acc.z += __shfl_xor(acc.z, 32, 64);
    acc.w += __shfl_xor(acc.w, 32, 64);
    if (lane < 32) part4[wv][c] = acc;
    __syncthreads();

    const float* partF = (const float*)part4;
    float y = 0.f;
    if (t < HD) {
#pragma unroll
        for (int w2 = 0; w2 < 16; ++w2) y += partF[w2 * HD + t];
        const float s2 = waveReduceSumAll(y * y);
        if (lane == 0) red2[t >> 6] = s2;
    }
    __syncthreads();
    if (t < HD) {
        const float scale = rsqrtf((red2[0] + red2[1]) * (1.f / HD) + EPS);
        gated[t] = y * scale * normw[t] * ws_zsig[h * HD + t];
    }
    __syncthreads();

    {
        const v4f* g4 = (const v4f*)gated;
        const v4f g0 = g4[j * 2], g1 = g4[j * 2 + 1];
        float a = w0.x * g0.x + w0.y * g0.y + w0.z * g0.z + w0.w * g0.w
                + w1.x * g1.x + w1.y * g1.y + w1.z * g1.z + w1.w * g1.w;
        a += __shfl_xor(a, 1, 64);
        a += __shfl_xor(a, 2, 64);
        a += __shfl_xor(a, 4, 64);
        a += __shfl_xor(a, 8, 64);
        if (j == 0) atomicAdd(&out[r], a);
    }
}

extern "C" void kernel_launch(void* const* d_in, const int* in_sizes, int n_in,
                              void* d_out, int out_size, void* d_ws, size_t ws_size,
                              hipStream_t stream) {
    const float* x     = (const float*)d_in[0];
    const float* state = (const float*)d_in[1];
    const float* conv  = (const float*)d_in[2];
    const float* Wqkv  = (const float*)d_in[3];
    const float* Wz    = (const float*)d_in[4];
    const float* Wa    = (const float*)d_in[5];
    const float* normw = (const float*)d_in[6];
    const float* Wout  = (const float*)d_in[7];

    float* out       = (float*)d_out;                    // [1024]
    float* new_state = out + H;                          // [16*128*128]
    float* conv_out  = new_state + (size_t)NH * HD * HD; // [18432]

    float* ws       = (float*)d_ws;
    float* ws_qkv   = ws;               // 6144
    float* ws_zsig  = ws + 6144;        // 2048
    float* ws_decay = ws + 8192;        // 16

    matvec_qkvza<<<MATVEC_BLOCKS + CONV_BLOCKS, 256, 0, stream>>>(
        x, Wqkv, Wz, Wa, conv, conv_out, out, ws_qkv, ws_zsig, ws_decay);
    state_gate_out<<<NH * 16, 1024, 0, stream>>>(
        state, ws_qkv, ws_decay, ws_zsig, normw, Wout, new_state, out);
}